// Round 4
// baseline (526.064 us; speedup 1.0000x reference)
//
#include <hip/hip_runtime.h>
#include <cmath>

#define NTOT 16384
#define NBATCH 8
#define NPRE 900
#define NPOST 64

// ---------------------------------------------------------------------------
// K1: fused MLP  h = relu(BN(W1@feat + b1)); off = W2@h + b2;
//     writes prop_out[b][n][4] = {xyz+off[0:3], off[3]} directly into d_out.
// fp32 GEMM, 128x128 tile, 8x8 per-thread with SPLIT column tile
// {tc*4..+3} u {64+tc*4..+3} -> B ds_read_b128 is 16 contiguous lanes
// (2-way bank alias = free) instead of 32B-stride 4-way conflict.
// ---------------------------------------------------------------------------
__global__ __launch_bounds__(256) void mlp_kernel(
    const float* __restrict__ feat, const float* __restrict__ xyz,
    const float* __restrict__ W1, const float* __restrict__ b1,
    const float* __restrict__ gamma, const float* __restrict__ beta,
    const float* __restrict__ rmean, const float* __restrict__ rvar,
    const float* __restrict__ W2, const float* __restrict__ b2,
    float* __restrict__ prop) {
  __shared__ float As[64][128];   // [k][m]  32 KB
  __shared__ float Bs[64][128];   // [k][n]  32 KB
  const int b  = blockIdx.y;
  const int n0 = blockIdx.x * 128;
  const int tid = threadIdx.x;
  const int tr = tid >> 4, tc = tid & 15;
  const float* fb = feat + (size_t)b * 256 * NTOT;

  float acc[8][8];
#pragma unroll
  for (int r = 0; r < 8; ++r)
#pragma unroll
    for (int c = 0; c < 8; ++c) acc[r][c] = 0.f;

  for (int kt = 0; kt < 4; ++kt) {
    // stage W1 tile transposed: As[k][m] = W1[m][kt*64+k]
    {
      const int m = tid & 127, qh = tid >> 7;
#pragma unroll
      for (int p = 0; p < 8; ++p) {
        const int q = qh + p * 2;                       // 0..15
        const float4 w = *(const float4*)(W1 + (size_t)m * 256 + kt * 64 + q * 4);
        As[q * 4 + 0][m] = w.x; As[q * 4 + 1][m] = w.y;
        As[q * 4 + 2][m] = w.z; As[q * 4 + 3][m] = w.w;
      }
      const int qq = tid & 31, r0 = tid >> 5;
#pragma unroll
      for (int p = 0; p < 8; ++p) {
        const int k = r0 + p * 8;
        *(float4*)(&Bs[k][qq * 4]) =
            *(const float4*)(fb + (size_t)(kt * 64 + k) * NTOT + n0 + qq * 4);
      }
    }
    __syncthreads();
#pragma unroll 8
    for (int k = 0; k < 64; ++k) {
      float a[8], bb[8];
      *(float4*)&a[0]  = *(const float4*)&As[k][tr * 8];
      *(float4*)&a[4]  = *(const float4*)&As[k][tr * 8 + 4];
      *(float4*)&bb[0] = *(const float4*)&Bs[k][tc * 4];        // 256B contig
      *(float4*)&bb[4] = *(const float4*)&Bs[k][64 + tc * 4];   // 256B contig
#pragma unroll
      for (int r = 0; r < 8; ++r)
#pragma unroll
        for (int c = 0; c < 8; ++c) acc[r][c] = fmaf(a[r], bb[c], acc[r][c]);
    }
    __syncthreads();
  }

  // epilogue: bias + BN + relu + W2 partials (cols: c<4 -> tc*4+c, else 64+...)
  float po[4][8];
#pragma unroll
  for (int kk = 0; kk < 4; ++kk)
#pragma unroll
    for (int c = 0; c < 8; ++c) po[kk][c] = 0.f;
#pragma unroll
  for (int r = 0; r < 8; ++r) {
    const int row = tr * 8 + r;
    const float inv = gamma[row] / sqrtf(rvar[row] + 1e-5f);
    const float sh  = beta[row] - rmean[row] * inv;
    const float bb1 = b1[row];
    float w2v[4];
#pragma unroll
    for (int kk = 0; kk < 4; ++kk) w2v[kk] = W2[kk * 128 + row];
#pragma unroll
    for (int c = 0; c < 8; ++c) {
      float h = (acc[r][c] + bb1) * inv + sh;
      h = fmaxf(h, 0.f);
#pragma unroll
      for (int kk = 0; kk < 4; ++kk) po[kk][c] += w2v[kk] * h;
    }
  }
  float* po_lds = &As[0][0];                    // [16][4][128] = 8192 f
#pragma unroll
  for (int kk = 0; kk < 4; ++kk)
#pragma unroll
    for (int c = 0; c < 8; ++c) {
      const int col = (c < 4) ? (tc * 4 + c) : (64 + tc * 4 + (c - 4));
      po_lds[((tr * 4 + kk) * 128) + col] = po[kk][c];
    }
  __syncthreads();
  float* off_lds = &Bs[0][0];                   // [4][128]
#pragma unroll
  for (int it = 0; it < 2; ++it) {
    const int idx = tid + it * 256;
    const int kk = idx >> 7, col = idx & 127;
    float sum = b2[kk];
#pragma unroll
    for (int t2 = 0; t2 < 16; ++t2) sum += po_lds[((t2 * 4 + kk) * 128) + col];
    off_lds[kk * 128 + col] = sum;
  }
  __syncthreads();
  if (tid < 128) {
    const int n = n0 + tid;
    const float* sx = xyz + ((size_t)b * NTOT + n) * 3;
    float4 o;
    o.x = sx[0] + off_lds[0 * 128 + tid];
    o.y = sx[1] + off_lds[1 * 128 + tid];
    o.z = sx[2] + off_lds[2 * 128 + tid];
    o.w = off_lds[3 * 128 + tid];
    *(float4*)(prop + ((size_t)b * NTOT + n) * 4) = o;
  }
}

// ---------------------------------------------------------------------------
// K2: exact top-NPRE selection via 32-bit threshold bisection on sigmoid bits,
//     then bitonic sort of <=1024 candidates (key<<32 | ~idx). Also emits
//     per-box corners, area, and AABB (for iou quick-reject).
// ---------------------------------------------------------------------------
__global__ __launch_bounds__(1024) void select_kernel(
    const float* __restrict__ cla, const float* __restrict__ prop,
    const float* __restrict__ tmpl, float* __restrict__ selbox,
    float* __restrict__ corners, float* __restrict__ areas,
    float* __restrict__ aabb) {
  __shared__ unsigned red[17];
  __shared__ int cnt_lds;
  __shared__ unsigned long long cand[1024];
  const int b = blockIdx.x, tid = threadIdx.x;
  unsigned key[16];
#pragma unroll
  for (int q = 0; q < 16; ++q) {
    const float x = cla[(size_t)b * NTOT + q * 1024 + tid];
    key[q] = __float_as_uint(1.0f / (1.0f + expf(-x)));
  }
  unsigned lo = 0u, hi = 0xFFFFFFFFu;
  while (hi - lo > 1u) {
    const unsigned mid = lo + ((hi - lo) >> 1);
    int c = 0;
#pragma unroll
    for (int q = 0; q < 16; ++q) c += (key[q] >= mid) ? 1 : 0;
#pragma unroll
    for (int off = 32; off > 0; off >>= 1) c += __shfl_down(c, off);
    __syncthreads();
    if ((tid & 63) == 0) red[tid >> 6] = (unsigned)c;
    __syncthreads();
    if (tid == 0) {
      unsigned s = 0;
      for (int w2 = 0; w2 < 16; ++w2) s += red[w2];
      red[16] = s;
    }
    __syncthreads();
    if (red[16] >= NPRE) lo = mid; else hi = mid;
  }
  const unsigned T = lo;
  if (tid == 0) cnt_lds = 0;
  cand[tid] = 0ull;
  __syncthreads();
#pragma unroll
  for (int q = 0; q < 16; ++q) {
    if (key[q] >= T) {
      const int pos = atomicAdd(&cnt_lds, 1);
      if (pos < 1024)
        cand[pos] = ((unsigned long long)key[q] << 32) |
                    (unsigned long long)(0xFFFFFFFFu - (unsigned)(q * 1024 + tid));
    }
  }
  __syncthreads();
  for (int k = 2; k <= 1024; k <<= 1) {
    for (int j = k >> 1; j > 0; j >>= 1) {
      if (tid < 512) {
        const int i = ((tid & ~(j - 1)) << 1) | (tid & (j - 1));
        const int l = i | j;
        const unsigned long long Pi = cand[i], Pl = cand[l];
        const bool asc = (i & k) == 0;
        if ((Pi < Pl) == asc) { cand[i] = Pl; cand[l] = Pi; }
      }
      __syncthreads();
    }
  }
  if (tid < NPRE) {
    const unsigned long long p = cand[tid];
    const int idx = (int)(0xFFFFFFFFu - (unsigned)(p & 0xFFFFFFFFull));
    const float score = __uint_as_float((unsigned)(p >> 32));
    const float4 pv = *(const float4*)(prop + ((size_t)b * NTOT + idx) * 4);
    const float d3 = tmpl[b * 7 + 3], d4 = tmpl[b * 7 + 4], d5 = tmpl[b * 7 + 5];
    const size_t o8 = ((size_t)b * NPRE + tid) * 8;
    selbox[o8 + 0] = pv.x; selbox[o8 + 1] = pv.y; selbox[o8 + 2] = pv.z;
    selbox[o8 + 3] = d3;   selbox[o8 + 4] = d4;   selbox[o8 + 5] = d5;
    selbox[o8 + 6] = pv.w; selbox[o8 + 7] = score;
    {
#pragma clang fp contract(off)
      const float cu = pv.x, cv = pv.z;
      const float hl = d5 * 0.5f, hw = d4 * 0.5f;
      const float x1 = cu - hl, y1 = cv - hw, x2 = cu + hl, y2 = cv + hw;
      const float cx = (x1 + x2) * 0.5f, cy = (y1 + y2) * 0.5f;
      const float hx = (x2 - x1) * 0.5f, hy = (y2 - y1) * 0.5f;
      const float cr = cosf(pv.w), sr = sinf(pv.w);
      const float lx[4] = {-hx, hx, hx, -hx};
      const float ly[4] = {-hy, -hy, hy, hy};
      float bx0 = 1e30f, by0 = 1e30f, bx1 = -1e30f, by1 = -1e30f;
#pragma unroll
      for (int q = 0; q < 4; ++q) {
        const float X = cx + cr * lx[q] - sr * ly[q];
        const float Y = cy + sr * lx[q] + cr * ly[q];
        corners[o8 + 2 * q]     = X;
        corners[o8 + 2 * q + 1] = Y;
        bx0 = fminf(bx0, X); by0 = fminf(by0, Y);
        bx1 = fmaxf(bx1, X); by1 = fmaxf(by1, Y);
      }
      areas[(size_t)b * NPRE + tid] = (x2 - x1) * (y2 - y1);
      float4 bb; bb.x = bx0; bb.y = by0; bb.z = bx1; bb.w = by1;
      *(float4*)(aabb + ((size_t)b * NPRE + tid) * 4) = bb;
    }
  }
}

// ---------------------------------------------------------------------------
// K3: pairwise rotated-IoU -> suppression bitmask. AABB quick-reject
// (conservative: AABB overlap >= true intersection; threshold 0.45*(ai+aj)
// vs exact 0.4594*(ai+aj) -> 1% margin >> fp error), register-only clip
// for survivors (statically unrolled 8-slot push chain, no LDS).
// ---------------------------------------------------------------------------
__device__ __forceinline__ float polyclip_reg(
    float s0x, float s0y, float s1x, float s1y,
    float s2x, float s2y, float s3x, float s3y,
    const float cjx[4], const float cjy[4]) {
#pragma clang fp contract(off)
  float vx[8], vy[8];
  vx[0] = s0x; vy[0] = s0y; vx[1] = s1x; vy[1] = s1y;
  vx[2] = s2x; vy[2] = s2y; vx[3] = s3x; vy[3] = s3y;
#pragma unroll
  for (int v = 4; v < 8; ++v) { vx[v] = 0.f; vy[v] = 0.f; }
  int cnt = 4;
#pragma unroll
  for (int e = 0; e < 4; ++e) {
    const float ax = cjx[e], ay = cjy[e];
    const float bx = cjx[(e + 1) & 3], by = cjy[(e + 1) & 3];
    const float nx = bx - ax, ny = by - ay;
    float d[8];
#pragma unroll
    for (int v = 0; v < 8; ++v) d[v] = nx * (vy[v] - ay) - ny * (vx[v] - ax);
    float ox[8], oy[8];
#pragma unroll
    for (int v = 0; v < 8; ++v) { ox[v] = 0.f; oy[v] = 0.f; }
    int oc = 0;
#pragma unroll
    for (int v = 0; v < 8; ++v) {
      const bool valid = v < cnt;
      float nvx, nvy, dn;
      if (v == 7) {
        const bool big = cnt > 8;
        nvx = big ? vx[7] : vx[0]; nvy = big ? vy[7] : vy[0]; dn = big ? d[7] : d[0];
      } else {
        const bool wrap = (v + 1 >= cnt);
        nvx = wrap ? vx[0] : vx[v + 1];
        nvy = wrap ? vy[0] : vy[v + 1];
        dn  = wrap ? d[0]  : d[v + 1];
      }
      const float dc = d[v];
      const bool inc = dc >= 0.f, inn = dn >= 0.f;
      const bool e1 = valid && inc;
#pragma unroll
      for (int s2 = 0; s2 < 8; ++s2) {
        const bool w_ = e1 && (oc == s2);
        ox[s2] = w_ ? vx[v] : ox[s2];
        oy[s2] = w_ ? vy[v] : oy[s2];
      }
      oc += e1 ? 1 : 0;
      const bool e2 = valid && (inc != inn);
      const float den = dc - dn;
      const float t = dc / ((den == 0.f) ? 1.0f : den);
      const float ipx = vx[v] + t * (nvx - vx[v]);
      const float ipy = vy[v] + t * (nvy - vy[v]);
#pragma unroll
      for (int s2 = 0; s2 < 8; ++s2) {
        const bool w_ = e2 && (oc == s2);
        ox[s2] = w_ ? ipx : ox[s2];
        oy[s2] = w_ ? ipy : oy[s2];
      }
      oc += e2 ? 1 : 0;
    }
#pragma unroll
    for (int v = 0; v < 8; ++v) { vx[v] = ox[v]; vy[v] = oy[v]; }
    cnt = oc;
  }
  float s = 0.f;
#pragma unroll
  for (int v = 0; v < 8; ++v) {
    const bool valid = (v < cnt) && (cnt >= 3);
    float jx, jy;
    if (v == 7) {
      const bool big = cnt > 8;
      jx = big ? vx[7] : vx[0]; jy = big ? vy[7] : vy[0];
    } else {
      const bool wrap = (v + 1 >= cnt);
      jx = wrap ? vx[0] : vx[v + 1]; jy = wrap ? vy[0] : vy[v + 1];
    }
    s += valid ? (vx[v] * jy - jx * vy[v]) : 0.f;
  }
  return fabsf(s) * 0.5f;
}

__global__ __launch_bounds__(256) void iou_kernel(
    const float* __restrict__ corners, const float* __restrict__ areas,
    const float* __restrict__ aabb, unsigned long long* __restrict__ sup) {
  const int i = blockIdx.x, b = blockIdx.y, tid = threadIdx.x;
  const float* ci = corners + ((size_t)b * NPRE + i) * 8;
  const float ai = areas[(size_t)b * NPRE + i];
  const float4 bi = *(const float4*)(aabb + ((size_t)b * NPRE + i) * 4);
  const float s0x = ci[0], s0y = ci[1], s1x = ci[2], s1y = ci[3];
  const float s2x = ci[4], s2y = ci[5], s3x = ci[6], s3y = ci[7];
  for (int c = 0; c < 4; ++c) {
    const int j = c * 256 + tid;
    bool bit = false;
    if (j > i && j < NPRE) {
      const float4 bj = *(const float4*)(aabb + ((size_t)b * NPRE + j) * 4);
      const float aj = areas[(size_t)b * NPRE + j];
      const float ow = fminf(bi.z, bj.z) - fmaxf(bi.x, bj.x);
      const float oh = fminf(bi.w, bj.w) - fmaxf(bi.y, bj.y);
      const float ov = fmaxf(ow, 0.f) * fmaxf(oh, 0.f);
      if (ov >= 0.45f * (ai + aj)) {
        const float* cj = corners + ((size_t)b * NPRE + j) * 8;
        float cjx[4], cjy[4];
#pragma unroll
        for (int q = 0; q < 4; ++q) { cjx[q] = cj[2 * q]; cjy[q] = cj[2 * q + 1]; }
        const float inter = polyclip_reg(s0x, s0y, s1x, s1y, s2x, s2y,
                                         s3x, s3y, cjx, cjy);
        const float iou = inter / fmaxf(ai + aj - inter, 1e-8f);
        bit = iou > 0.85f;
      }
    }
    const unsigned long long m = __ballot(bit);
    if ((tid & 63) == 0)
      sup[((size_t)b * NPRE + i) * 16 + (unsigned)(j >> 6)] = m;
  }
}

// ---------------------------------------------------------------------------
// K4: sequential NMS. LDS-staged sup matrix, 4-deep static prefetch.
// ---------------------------------------------------------------------------
#define NMS_ROWS 904
__global__ __launch_bounds__(1024) void nms_kernel(
    const unsigned long long* __restrict__ sup,
    unsigned long long* __restrict__ keepw) {
  extern __shared__ unsigned long long rows[];   // NMS_ROWS*16*8 = 115,712 B
  const int b = blockIdx.x, tid = threadIdx.x;
  const unsigned long long* srow = sup + (size_t)b * NPRE * 16;
  for (int q = tid; q < NMS_ROWS * 16; q += 1024)
    rows[q] = (q < NPRE * 16) ? srow[q] : 0ull;
  __syncthreads();
  if (tid < 64) {
    const int lane = tid;
    const bool ld = lane < 16;
    unsigned long long kw = 0ull;
    if (lane < 14) kw = ~0ull;
    else if (lane == 14) kw = 0xFull;            // bits 896..899
    unsigned long long r0 = ld ? rows[0 * 16 + lane] : 0ull;
    unsigned long long r1 = ld ? rows[1 * 16 + lane] : 0ull;
    unsigned long long r2 = ld ? rows[2 * 16 + lane] : 0ull;
    unsigned long long r3 = ld ? rows[3 * 16 + lane] : 0ull;
#define NMS_STEP(ii, bufv)                                            \
    {                                                                 \
      const unsigned long long w = __shfl(kw, (ii) >> 6);             \
      if ((w >> ((ii) & 63)) & 1ull) kw &= ~(bufv);                   \
      bufv = ld ? rows[((ii) + 4) * 16 + lane] : 0ull;                \
    }
    for (int i = 0; i < NPRE; i += 4) {
      NMS_STEP(i + 0, r0)
      NMS_STEP(i + 1, r1)
      NMS_STEP(i + 2, r2)
      NMS_STEP(i + 3, r3)
    }
#undef NMS_STEP
    if (lane < 15) keepw[b * 16 + lane] = kw;
  }
}

// ---------------------------------------------------------------------------
// K5: zero outputs, rank kept boxes, scatter top-64.
// ---------------------------------------------------------------------------
__global__ __launch_bounds__(128) void out_kernel(
    const float* __restrict__ selbox,
    const unsigned long long* __restrict__ keepw, float* __restrict__ out) {
  const int b = blockIdx.x, t = threadIdx.x;
  float* retb = out + (size_t)b * (NPOST * 7);
  float* rets = out + (size_t)NBATCH * NPOST * 7 + (size_t)b * NPOST;
  float* cent = out + (size_t)NBATCH * NPOST * 7 + (size_t)NBATCH * NPOST +
                (size_t)NBATCH * NTOT * 4 + (size_t)b * (NPOST * 3);
  for (int q = t; q < NPOST * 7; q += 128) retb[q] = 0.f;
  if (t < NPOST) rets[t] = 0.f;
  for (int q = t; q < NPOST * 3; q += 128) cent[q] = 0.f;
  __syncthreads();
  if (t < 64) {
    const unsigned long long kws = (t < 15) ? keepw[b * 16 + t] : 0ull;
    const int pc = __popcll(kws);
    int inc = pc;
    for (int d2 = 1; d2 < 64; d2 <<= 1) {
      const int up = __shfl_up(inc, d2);
      if (t >= d2) inc += up;
    }
    const int ex = inc - pc;
    for (int it = 0; it < 15; ++it) {
      const int i = t + it * 64;
      const int w = (i >> 6) & 63;
      const unsigned long long kword = __shfl(kws, w);
      const int exw = __shfl(ex, w);
      if (i < NPRE) {
        const int bp = i & 63;
        if ((kword >> bp) & 1ull) {
          const int rank =
              exw + __popcll(kword & (((unsigned long long)1 << bp) - 1ull));
          if (rank < NPOST) {
            const float* sb = selbox + ((size_t)b * NPRE + i) * 8;
#pragma unroll
            for (int c = 0; c < 7; ++c) retb[rank * 7 + c] = sb[c];
            rets[rank] = sb[7];
            cent[rank * 3 + 0] = sb[0];
            cent[rank * 3 + 1] = sb[1];
            cent[rank * 3 + 2] = sb[2];
          }
        }
      }
    }
  }
}

// ---------------------------------------------------------------------------
extern "C" void kernel_launch(void* const* d_in, const int* in_sizes, int n_in,
                              void* d_out, int out_size, void* d_ws, size_t ws_size,
                              hipStream_t stream) {
  const float* xyz   = (const float*)d_in[0];
  const float* feat  = (const float*)d_in[1];
  const float* cla   = (const float*)d_in[2];
  const float* tmpl  = (const float*)d_in[3];
  const float* W1    = (const float*)d_in[4];
  const float* b1    = (const float*)d_in[5];
  const float* gamma = (const float*)d_in[6];
  const float* beta  = (const float*)d_in[7];
  const float* rmean = (const float*)d_in[8];
  const float* rvar  = (const float*)d_in[9];
  const float* W2    = (const float*)d_in[10];
  const float* b2    = (const float*)d_in[11];
  float* out  = (float*)d_out;
  float* prop = out + (size_t)NBATCH * NPOST * 7 + (size_t)NBATCH * NPOST;

  char* ws = (char*)d_ws;
  float* selbox  = (float*)(ws);                               // 230400 B
  float* corners = (float*)(ws + 230400);                      // 230400 B
  float* areas   = (float*)(ws + 460800);                      // 28800 B
  float* aabb    = (float*)(ws + 489600);                      // 115200 B
  unsigned long long* sup   = (unsigned long long*)(ws + 604800);   // 921600 B
  unsigned long long* keepw = (unsigned long long*)(ws + 1526400);  // 1024 B

  mlp_kernel<<<dim3(NTOT / 128, NBATCH), 256, 0, stream>>>(
      feat, xyz, W1, b1, gamma, beta, rmean, rvar, W2, b2, prop);

  select_kernel<<<NBATCH, 1024, 0, stream>>>(cla, prop, tmpl, selbox, corners,
                                             areas, aabb);

  iou_kernel<<<dim3(NPRE, NBATCH), 256, 0, stream>>>(corners, areas, aabb, sup);

  (void)hipFuncSetAttribute((const void*)nms_kernel,
                            hipFuncAttributeMaxDynamicSharedMemorySize,
                            NMS_ROWS * 16 * (int)sizeof(unsigned long long));
  nms_kernel<<<NBATCH, 1024, NMS_ROWS * 16 * sizeof(unsigned long long),
               stream>>>(sup, keepw);

  out_kernel<<<NBATCH, 128, 0, stream>>>(selbox, keepw, out);
}

// Round 5
// 477.212 us; speedup vs baseline: 1.1024x; 1.1024x over previous
//
#include <hip/hip_runtime.h>
#include <cmath>

#define NTOT 16384
#define NBATCH 8
#define NPRE 900
#define NPOST 64

// ---------------------------------------------------------------------------
// K1: fused MLP  h = relu(BN(W1@feat + b1)); off = W2@h + b2;
//     writes prop_out[b][n][4] = {xyz+off[0:3], off[3]} directly into d_out.
// fp32 GEMM, 128x128 tile, 8x8 per-thread with SPLIT column tile
// {tc*4..+3} u {64+tc*4..+3} -> B ds_read_b128 is 16 contiguous lanes
// (2-way bank alias = free) instead of 32B-stride 4-way conflict.
// ---------------------------------------------------------------------------
__global__ __launch_bounds__(256) void mlp_kernel(
    const float* __restrict__ feat, const float* __restrict__ xyz,
    const float* __restrict__ W1, const float* __restrict__ b1,
    const float* __restrict__ gamma, const float* __restrict__ beta,
    const float* __restrict__ rmean, const float* __restrict__ rvar,
    const float* __restrict__ W2, const float* __restrict__ b2,
    float* __restrict__ prop) {
  __shared__ float As[64][128];   // [k][m]  32 KB
  __shared__ float Bs[64][128];   // [k][n]  32 KB
  const int b  = blockIdx.y;
  const int n0 = blockIdx.x * 128;
  const int tid = threadIdx.x;
  const int tr = tid >> 4, tc = tid & 15;
  const float* fb = feat + (size_t)b * 256 * NTOT;

  float acc[8][8];
#pragma unroll
  for (int r = 0; r < 8; ++r)
#pragma unroll
    for (int c = 0; c < 8; ++c) acc[r][c] = 0.f;

  for (int kt = 0; kt < 4; ++kt) {
    // stage W1 tile transposed: As[k][m] = W1[m][kt*64+k]
    {
      const int m = tid & 127, qh = tid >> 7;
#pragma unroll
      for (int p = 0; p < 8; ++p) {
        const int q = qh + p * 2;                       // 0..15
        const float4 w = *(const float4*)(W1 + (size_t)m * 256 + kt * 64 + q * 4);
        As[q * 4 + 0][m] = w.x; As[q * 4 + 1][m] = w.y;
        As[q * 4 + 2][m] = w.z; As[q * 4 + 3][m] = w.w;
      }
      const int qq = tid & 31, r0 = tid >> 5;
#pragma unroll
      for (int p = 0; p < 8; ++p) {
        const int k = r0 + p * 8;
        *(float4*)(&Bs[k][qq * 4]) =
            *(const float4*)(fb + (size_t)(kt * 64 + k) * NTOT + n0 + qq * 4);
      }
    }
    __syncthreads();
#pragma unroll 8
    for (int k = 0; k < 64; ++k) {
      float a[8], bb[8];
      *(float4*)&a[0]  = *(const float4*)&As[k][tr * 8];
      *(float4*)&a[4]  = *(const float4*)&As[k][tr * 8 + 4];
      *(float4*)&bb[0] = *(const float4*)&Bs[k][tc * 4];        // 256B contig
      *(float4*)&bb[4] = *(const float4*)&Bs[k][64 + tc * 4];   // 256B contig
#pragma unroll
      for (int r = 0; r < 8; ++r)
#pragma unroll
        for (int c = 0; c < 8; ++c) acc[r][c] = fmaf(a[r], bb[c], acc[r][c]);
    }
    __syncthreads();
  }

  // epilogue: bias + BN + relu + W2 partials (cols: c<4 -> tc*4+c, else 64+...)
  float po[4][8];
#pragma unroll
  for (int kk = 0; kk < 4; ++kk)
#pragma unroll
    for (int c = 0; c < 8; ++c) po[kk][c] = 0.f;
#pragma unroll
  for (int r = 0; r < 8; ++r) {
    const int row = tr * 8 + r;
    const float inv = gamma[row] / sqrtf(rvar[row] + 1e-5f);
    const float sh  = beta[row] - rmean[row] * inv;
    const float bb1 = b1[row];
    float w2v[4];
#pragma unroll
    for (int kk = 0; kk < 4; ++kk) w2v[kk] = W2[kk * 128 + row];
#pragma unroll
    for (int c = 0; c < 8; ++c) {
      float h = (acc[r][c] + bb1) * inv + sh;
      h = fmaxf(h, 0.f);
#pragma unroll
      for (int kk = 0; kk < 4; ++kk) po[kk][c] += w2v[kk] * h;
    }
  }
  float* po_lds = &As[0][0];                    // [16][4][128] = 8192 f
#pragma unroll
  for (int kk = 0; kk < 4; ++kk)
#pragma unroll
    for (int c = 0; c < 8; ++c) {
      const int col = (c < 4) ? (tc * 4 + c) : (64 + tc * 4 + (c - 4));
      po_lds[((tr * 4 + kk) * 128) + col] = po[kk][c];
    }
  __syncthreads();
  float* off_lds = &Bs[0][0];                   // [4][128]
#pragma unroll
  for (int it = 0; it < 2; ++it) {
    const int idx = tid + it * 256;
    const int kk = idx >> 7, col = idx & 127;
    float sum = b2[kk];
#pragma unroll
    for (int t2 = 0; t2 < 16; ++t2) sum += po_lds[((t2 * 4 + kk) * 128) + col];
    off_lds[kk * 128 + col] = sum;
  }
  __syncthreads();
  if (tid < 128) {
    const int n = n0 + tid;
    const float* sx = xyz + ((size_t)b * NTOT + n) * 3;
    float4 o;
    o.x = sx[0] + off_lds[0 * 128 + tid];
    o.y = sx[1] + off_lds[1 * 128 + tid];
    o.z = sx[2] + off_lds[2 * 128 + tid];
    o.w = off_lds[3 * 128 + tid];
    *(float4*)(prop + ((size_t)b * NTOT + n) * 4) = o;
  }
}

// ---------------------------------------------------------------------------
// shared clip routine: register-only Sutherland-Hodgman, 8-slot cndmask push
// chains (exact reference semantics incl. OOB drop / gather clamp).
// ---------------------------------------------------------------------------
__device__ __forceinline__ float polyclip_reg(
    float s0x, float s0y, float s1x, float s1y,
    float s2x, float s2y, float s3x, float s3y,
    const float cjx[4], const float cjy[4]) {
#pragma clang fp contract(off)
  float vx[8], vy[8];
  vx[0] = s0x; vy[0] = s0y; vx[1] = s1x; vy[1] = s1y;
  vx[2] = s2x; vy[2] = s2y; vx[3] = s3x; vy[3] = s3y;
#pragma unroll
  for (int v = 4; v < 8; ++v) { vx[v] = 0.f; vy[v] = 0.f; }
  int cnt = 4;
#pragma unroll
  for (int e = 0; e < 4; ++e) {
    const float ax = cjx[e], ay = cjy[e];
    const float bx = cjx[(e + 1) & 3], by = cjy[(e + 1) & 3];
    const float nx = bx - ax, ny = by - ay;
    float d[8];
#pragma unroll
    for (int v = 0; v < 8; ++v) d[v] = nx * (vy[v] - ay) - ny * (vx[v] - ax);
    float ox[8], oy[8];
#pragma unroll
    for (int v = 0; v < 8; ++v) { ox[v] = 0.f; oy[v] = 0.f; }
    int oc = 0;
#pragma unroll
    for (int v = 0; v < 8; ++v) {
      const bool valid = v < cnt;
      float nvx, nvy, dn;
      if (v == 7) {
        const bool big = cnt > 8;
        nvx = big ? vx[7] : vx[0]; nvy = big ? vy[7] : vy[0]; dn = big ? d[7] : d[0];
      } else {
        const bool wrap = (v + 1 >= cnt);
        nvx = wrap ? vx[0] : vx[v + 1];
        nvy = wrap ? vy[0] : vy[v + 1];
        dn  = wrap ? d[0]  : d[v + 1];
      }
      const float dc = d[v];
      const bool inc = dc >= 0.f, inn = dn >= 0.f;
      const bool e1 = valid && inc;
#pragma unroll
      for (int s2 = 0; s2 < 8; ++s2) {
        const bool w_ = e1 && (oc == s2);
        ox[s2] = w_ ? vx[v] : ox[s2];
        oy[s2] = w_ ? vy[v] : oy[s2];
      }
      oc += e1 ? 1 : 0;
      const bool e2 = valid && (inc != inn);
      const float den = dc - dn;
      const float t = dc / ((den == 0.f) ? 1.0f : den);
      const float ipx = vx[v] + t * (nvx - vx[v]);
      const float ipy = vy[v] + t * (nvy - vy[v]);
#pragma unroll
      for (int s2 = 0; s2 < 8; ++s2) {
        const bool w_ = e2 && (oc == s2);
        ox[s2] = w_ ? ipx : ox[s2];
        oy[s2] = w_ ? ipy : oy[s2];
      }
      oc += e2 ? 1 : 0;
    }
#pragma unroll
    for (int v = 0; v < 8; ++v) { vx[v] = ox[v]; vy[v] = oy[v]; }
    cnt = oc;
  }
  float s = 0.f;
#pragma unroll
  for (int v = 0; v < 8; ++v) {
    const bool valid = (v < cnt) && (cnt >= 3);
    float jx, jy;
    if (v == 7) {
      const bool big = cnt > 8;
      jx = big ? vx[7] : vx[0]; jy = big ? vy[7] : vy[0];
    } else {
      const bool wrap = (v + 1 >= cnt);
      jx = wrap ? vx[0] : vx[v + 1]; jy = wrap ? vy[0] : vy[v + 1];
    }
    s += valid ? (vx[v] * jy - jx * vy[v]) : 0.f;
  }
  return fabsf(s) * 0.5f;
}

__device__ __forceinline__ bool pair_suppressed(
    const float* __restrict__ corners, const float* __restrict__ areas,
    int b, int i, int j) {
  const float* ci = corners + ((size_t)b * NPRE + i) * 8;
  const float* cj = corners + ((size_t)b * NPRE + j) * 8;
  float cjx[4], cjy[4];
#pragma unroll
  for (int q = 0; q < 4; ++q) { cjx[q] = cj[2 * q]; cjy[q] = cj[2 * q + 1]; }
  const float inter = polyclip_reg(ci[0], ci[1], ci[2], ci[3],
                                   ci[4], ci[5], ci[6], ci[7], cjx, cjy);
  const float ai = areas[(size_t)b * NPRE + i];
  const float aj = areas[(size_t)b * NPRE + j];
  const float iou = inter / fmaxf(ai + aj - inter, 1e-8f);
  return iou > 0.85f;
}

// ---------------------------------------------------------------------------
// K2: exact top-NPRE selection via threshold bisection on sigmoid bits with
//     EARLY EXIT (any T with count in [NPRE,1024] yields the identical
//     top-NPRE after the tie-broken sort). Emits corners/area/aabb and
//     zeroes the pairgen worklist counters.
// ---------------------------------------------------------------------------
__global__ __launch_bounds__(1024) void select_kernel(
    const float* __restrict__ cla, const float* __restrict__ prop,
    const float* __restrict__ tmpl, float* __restrict__ selbox,
    float* __restrict__ corners, float* __restrict__ areas,
    float* __restrict__ aabb, int* __restrict__ wlcnt) {
  __shared__ unsigned red[17];
  __shared__ int cnt_lds;
  __shared__ unsigned long long cand[1024];
  const int b = blockIdx.x, tid = threadIdx.x;
  if (tid == 0) wlcnt[b] = 0;                  // consumed by pairgen (next kernel)
  unsigned key[16];
#pragma unroll
  for (int q = 0; q < 16; ++q) {
    const float x = cla[(size_t)b * NTOT + q * 1024 + tid];
    key[q] = __float_as_uint(1.0f / (1.0f + expf(-x)));
  }
  unsigned lo = 0u, hi = 0xFFFFFFFFu;
  unsigned T = 0u;
  bool done = false;
  while (!done && (hi - lo > 1u)) {
    const unsigned mid = lo + ((hi - lo) >> 1);
    int c = 0;
#pragma unroll
    for (int q = 0; q < 16; ++q) c += (key[q] >= mid) ? 1 : 0;
#pragma unroll
    for (int off = 32; off > 0; off >>= 1) c += __shfl_down(c, off);
    __syncthreads();
    if ((tid & 63) == 0) red[tid >> 6] = (unsigned)c;
    __syncthreads();
    if (tid == 0) {
      unsigned s = 0;
      for (int w2 = 0; w2 < 16; ++w2) s += red[w2];
      red[16] = s;
    }
    __syncthreads();
    const unsigned cntv = red[16];
    if (cntv >= NPRE && cntv <= 1024) { T = mid; done = true; }
    else if (cntv >= NPRE) lo = mid;
    else hi = mid;
  }
  if (!done) T = lo;
  if (tid == 0) cnt_lds = 0;
  cand[tid] = 0ull;
  __syncthreads();
#pragma unroll
  for (int q = 0; q < 16; ++q) {
    if (key[q] >= T) {
      const int pos = atomicAdd(&cnt_lds, 1);
      if (pos < 1024)
        cand[pos] = ((unsigned long long)key[q] << 32) |
                    (unsigned long long)(0xFFFFFFFFu - (unsigned)(q * 1024 + tid));
    }
  }
  __syncthreads();
  for (int k = 2; k <= 1024; k <<= 1) {
    for (int j = k >> 1; j > 0; j >>= 1) {
      if (tid < 512) {
        const int i = ((tid & ~(j - 1)) << 1) | (tid & (j - 1));
        const int l = i | j;
        const unsigned long long Pi = cand[i], Pl = cand[l];
        const bool asc = (i & k) == 0;
        if ((Pi < Pl) == asc) { cand[i] = Pl; cand[l] = Pi; }
      }
      __syncthreads();
    }
  }
  if (tid < NPRE) {
    const unsigned long long p = cand[tid];
    const int idx = (int)(0xFFFFFFFFu - (unsigned)(p & 0xFFFFFFFFull));
    const float score = __uint_as_float((unsigned)(p >> 32));
    const float4 pv = *(const float4*)(prop + ((size_t)b * NTOT + idx) * 4);
    const float d3 = tmpl[b * 7 + 3], d4 = tmpl[b * 7 + 4], d5 = tmpl[b * 7 + 5];
    const size_t o8 = ((size_t)b * NPRE + tid) * 8;
    selbox[o8 + 0] = pv.x; selbox[o8 + 1] = pv.y; selbox[o8 + 2] = pv.z;
    selbox[o8 + 3] = d3;   selbox[o8 + 4] = d4;   selbox[o8 + 5] = d5;
    selbox[o8 + 6] = pv.w; selbox[o8 + 7] = score;
    {
#pragma clang fp contract(off)
      const float cu = pv.x, cv = pv.z;
      const float hl = d5 * 0.5f, hw = d4 * 0.5f;
      const float x1 = cu - hl, y1 = cv - hw, x2 = cu + hl, y2 = cv + hw;
      const float cx = (x1 + x2) * 0.5f, cy = (y1 + y2) * 0.5f;
      const float hx = (x2 - x1) * 0.5f, hy = (y2 - y1) * 0.5f;
      const float cr = cosf(pv.w), sr = sinf(pv.w);
      const float lx[4] = {-hx, hx, hx, -hx};
      const float ly[4] = {-hy, -hy, hy, hy};
      float bx0 = 1e30f, by0 = 1e30f, bx1 = -1e30f, by1 = -1e30f;
#pragma unroll
      for (int q = 0; q < 4; ++q) {
        const float X = cx + cr * lx[q] - sr * ly[q];
        const float Y = cy + sr * lx[q] + cr * ly[q];
        corners[o8 + 2 * q]     = X;
        corners[o8 + 2 * q + 1] = Y;
        bx0 = fminf(bx0, X); by0 = fminf(by0, Y);
        bx1 = fmaxf(bx1, X); by1 = fmaxf(by1, Y);
      }
      areas[(size_t)b * NPRE + tid] = (x2 - x1) * (y2 - y1);
      float4 bb; bb.x = bx0; bb.y = by0; bb.z = bx1; bb.w = by1;
      *(float4*)(aabb + ((size_t)b * NPRE + tid) * 4) = bb;
    }
  }
}

// ---------------------------------------------------------------------------
// K3a: pairgen — AABB quick-test, compact passing pairs into per-batch
// worklist (ballot/scan, one atomicAdd per block), zero own sup row.
// Overflow pairs (worklist full) are clipped INLINE -> always correct.
// ---------------------------------------------------------------------------
__global__ __launch_bounds__(256) void pairgen_kernel(
    const float* __restrict__ aabb, const float* __restrict__ areas,
    const float* __restrict__ corners, unsigned long long* __restrict__ sup,
    unsigned* __restrict__ wl, int* __restrict__ wlcnt, int cap) {
  __shared__ int wsum[4];
  __shared__ int base_s;
  const int i = blockIdx.x, b = blockIdx.y, tid = threadIdx.x;
  if (tid < 16) sup[((size_t)b * NPRE + i) * 16 + tid] = 0ull;
  const float4 bi = *(const float4*)(aabb + ((size_t)b * NPRE + i) * 4);
  const float ai = areas[(size_t)b * NPRE + i];
  bool pass[4];
  int pc = 0;
#pragma unroll
  for (int c = 0; c < 4; ++c) {
    const int j = c * 256 + tid;
    bool p = false;
    if (j > i && j < NPRE) {
      const float4 bj = *(const float4*)(aabb + ((size_t)b * NPRE + j) * 4);
      const float aj = areas[(size_t)b * NPRE + j];
      const float ow = fminf(bi.z, bj.z) - fmaxf(bi.x, bj.x);
      const float oh = fminf(bi.w, bj.w) - fmaxf(bi.y, bj.y);
      const float ov = fmaxf(ow, 0.f) * fmaxf(oh, 0.f);
      p = (ov >= 0.45f * (ai + aj));
    }
    pass[c] = p;
    pc += p ? 1 : 0;
  }
  // block exclusive scan of per-thread counts
  int inc = pc;
#pragma unroll
  for (int d2 = 1; d2 < 64; d2 <<= 1) {
    const int u = __shfl_up(inc, d2);
    if ((tid & 63) >= d2) inc += u;
  }
  if ((tid & 63) == 63) wsum[tid >> 6] = inc;
  __syncthreads();
  if (tid == 0) {
    const int tot = wsum[0] + wsum[1] + wsum[2] + wsum[3];
    base_s = (tot > 0) ? atomicAdd(&wlcnt[b], tot) : 0;
  }
  __syncthreads();
  int wbase = 0;
#pragma unroll
  for (int w = 0; w < 4; ++w)
    if (w < (tid >> 6)) wbase += wsum[w];
  int myoff = base_s + wbase + (inc - pc);   // exclusive position
#pragma unroll
  for (int c = 0; c < 4; ++c) {
    if (pass[c]) {
      const int j = c * 256 + tid;
      const int pos = myoff++;
      if (pos < cap) {
        wl[(size_t)b * cap + pos] = (unsigned)((i << 10) | j);
      } else {
        // overflow fallback: clip inline (rare/never; correctness guard)
        if (pair_suppressed(corners, areas, b, i, j))
          atomicOr(&sup[((size_t)b * NPRE + i) * 16 + (j >> 6)],
                   1ull << (j & 63));
      }
    }
  }
}

// ---------------------------------------------------------------------------
// K3b: clip — dense worklist, one pair per lane, exact clip, atomicOr bit.
// ---------------------------------------------------------------------------
__global__ __launch_bounds__(256) void clip_kernel(
    const float* __restrict__ corners, const float* __restrict__ areas,
    const unsigned* __restrict__ wl, const int* __restrict__ wlcnt, int cap,
    unsigned long long* __restrict__ sup) {
  const int b = blockIdx.y, tid = threadIdx.x;
  const int n = min(wlcnt[b], cap);
  for (int idx = blockIdx.x * 256 + tid; idx < n; idx += gridDim.x * 256) {
    const unsigned e = wl[(size_t)b * cap + idx];
    const int i = (int)(e >> 10), j = (int)(e & 1023u);
    if (pair_suppressed(corners, areas, b, i, j))
      atomicOr(&sup[((size_t)b * NPRE + i) * 16 + (j >> 6)], 1ull << (j & 63));
  }
}

// ---------------------------------------------------------------------------
// K4: sequential NMS. LDS-staged sup matrix, 4-deep static prefetch.
// ---------------------------------------------------------------------------
#define NMS_ROWS 904
__global__ __launch_bounds__(1024) void nms_kernel(
    const unsigned long long* __restrict__ sup,
    unsigned long long* __restrict__ keepw) {
  extern __shared__ unsigned long long rows[];   // NMS_ROWS*16*8 = 115,712 B
  const int b = blockIdx.x, tid = threadIdx.x;
  const unsigned long long* srow = sup + (size_t)b * NPRE * 16;
  for (int q = tid; q < NMS_ROWS * 16; q += 1024)
    rows[q] = (q < NPRE * 16) ? srow[q] : 0ull;
  __syncthreads();
  if (tid < 64) {
    const int lane = tid;
    const bool ld = lane < 16;
    unsigned long long kw = 0ull;
    if (lane < 14) kw = ~0ull;
    else if (lane == 14) kw = 0xFull;            // bits 896..899
    unsigned long long r0 = ld ? rows[0 * 16 + lane] : 0ull;
    unsigned long long r1 = ld ? rows[1 * 16 + lane] : 0ull;
    unsigned long long r2 = ld ? rows[2 * 16 + lane] : 0ull;
    unsigned long long r3 = ld ? rows[3 * 16 + lane] : 0ull;
#define NMS_STEP(ii, bufv)                                            \
    {                                                                 \
      const unsigned long long w = __shfl(kw, (ii) >> 6);             \
      if ((w >> ((ii) & 63)) & 1ull) kw &= ~(bufv);                   \
      bufv = ld ? rows[((ii) + 4) * 16 + lane] : 0ull;                \
    }
    for (int i = 0; i < NPRE; i += 4) {
      NMS_STEP(i + 0, r0)
      NMS_STEP(i + 1, r1)
      NMS_STEP(i + 2, r2)
      NMS_STEP(i + 3, r3)
    }
#undef NMS_STEP
    if (lane < 15) keepw[b * 16 + lane] = kw;
  }
}

// ---------------------------------------------------------------------------
// K5: zero outputs, rank kept boxes, scatter top-64.
// ---------------------------------------------------------------------------
__global__ __launch_bounds__(128) void out_kernel(
    const float* __restrict__ selbox,
    const unsigned long long* __restrict__ keepw, float* __restrict__ out) {
  const int b = blockIdx.x, t = threadIdx.x;
  float* retb = out + (size_t)b * (NPOST * 7);
  float* rets = out + (size_t)NBATCH * NPOST * 7 + (size_t)b * NPOST;
  float* cent = out + (size_t)NBATCH * NPOST * 7 + (size_t)NBATCH * NPOST +
                (size_t)NBATCH * NTOT * 4 + (size_t)b * (NPOST * 3);
  for (int q = t; q < NPOST * 7; q += 128) retb[q] = 0.f;
  if (t < NPOST) rets[t] = 0.f;
  for (int q = t; q < NPOST * 3; q += 128) cent[q] = 0.f;
  __syncthreads();
  if (t < 64) {
    const unsigned long long kws = (t < 15) ? keepw[b * 16 + t] : 0ull;
    const int pc = __popcll(kws);
    int inc = pc;
    for (int d2 = 1; d2 < 64; d2 <<= 1) {
      const int up = __shfl_up(inc, d2);
      if (t >= d2) inc += up;
    }
    const int ex = inc - pc;
    for (int it = 0; it < 15; ++it) {
      const int i = t + it * 64;
      const int w = (i >> 6) & 63;
      const unsigned long long kword = __shfl(kws, w);
      const int exw = __shfl(ex, w);
      if (i < NPRE) {
        const int bp = i & 63;
        if ((kword >> bp) & 1ull) {
          const int rank =
              exw + __popcll(kword & (((unsigned long long)1 << bp) - 1ull));
          if (rank < NPOST) {
            const float* sb = selbox + ((size_t)b * NPRE + i) * 8;
#pragma unroll
            for (int c = 0; c < 7; ++c) retb[rank * 7 + c] = sb[c];
            rets[rank] = sb[7];
            cent[rank * 3 + 0] = sb[0];
            cent[rank * 3 + 1] = sb[1];
            cent[rank * 3 + 2] = sb[2];
          }
        }
      }
    }
  }
}

// ---------------------------------------------------------------------------
extern "C" void kernel_launch(void* const* d_in, const int* in_sizes, int n_in,
                              void* d_out, int out_size, void* d_ws, size_t ws_size,
                              hipStream_t stream) {
  const float* xyz   = (const float*)d_in[0];
  const float* feat  = (const float*)d_in[1];
  const float* cla   = (const float*)d_in[2];
  const float* tmpl  = (const float*)d_in[3];
  const float* W1    = (const float*)d_in[4];
  const float* b1    = (const float*)d_in[5];
  const float* gamma = (const float*)d_in[6];
  const float* beta  = (const float*)d_in[7];
  const float* rmean = (const float*)d_in[8];
  const float* rvar  = (const float*)d_in[9];
  const float* W2    = (const float*)d_in[10];
  const float* b2    = (const float*)d_in[11];
  float* out  = (float*)d_out;
  float* prop = out + (size_t)NBATCH * NPOST * 7 + (size_t)NBATCH * NPOST;

  char* ws = (char*)d_ws;
  float* selbox  = (float*)(ws);                                   // 230400 B
  float* corners = (float*)(ws + 230400);                          // 230400 B
  float* areas   = (float*)(ws + 460800);                          // 28800 B
  float* aabb    = (float*)(ws + 489600);                          // 115200 B
  unsigned long long* sup   = (unsigned long long*)(ws + 604800);  // 921600 B
  unsigned long long* keepw = (unsigned long long*)(ws + 1526400); // 1024 B
  int* wlcnt = (int*)(ws + 1527424);                               // 32 B
  unsigned* wl = (unsigned*)(ws + 1527456);
  long long avail = (long long)ws_size - 1527456;
  if (avail < 0) avail = 0;
  int cap = (int)(avail / (4 * NBATCH));
  if (cap > 404551) cap = 404551;   // max j>i pairs per batch

  mlp_kernel<<<dim3(NTOT / 128, NBATCH), 256, 0, stream>>>(
      feat, xyz, W1, b1, gamma, beta, rmean, rvar, W2, b2, prop);

  select_kernel<<<NBATCH, 1024, 0, stream>>>(cla, prop, tmpl, selbox, corners,
                                             areas, aabb, wlcnt);

  pairgen_kernel<<<dim3(NPRE, NBATCH), 256, 0, stream>>>(
      aabb, areas, corners, sup, wl, wlcnt, cap);

  clip_kernel<<<dim3(64, NBATCH), 256, 0, stream>>>(corners, areas, wl, wlcnt,
                                                    cap, sup);

  (void)hipFuncSetAttribute((const void*)nms_kernel,
                            hipFuncAttributeMaxDynamicSharedMemorySize,
                            NMS_ROWS * 16 * (int)sizeof(unsigned long long));
  nms_kernel<<<NBATCH, 1024, NMS_ROWS * 16 * sizeof(unsigned long long),
               stream>>>(sup, keepw);

  out_kernel<<<NBATCH, 128, 0, stream>>>(selbox, keepw, out);
}